// Round 5
// baseline (111.659 us; speedup 1.0000x reference)
//
#include <hip/hip_runtime.h>

// HMM posterior: out[b,t,s] = log_softmax_s(alphahat[t]+betahat[t]) — batch-independent
// (per-(b,t) emission scalars cancel in the state-axis softmax; observations unused).
// Linear space: p_t = p0 E^t, q_t = E^(1023-t) 1, E = exp(logA)/max. Global scale of
// p,q cancels in the final log-softmax -> NO per-step rescale in the per-t chains.
//
// BASE-4 decomposition (round-5): table holds 15 matrices E^(d*4^j), j=0..4, d=1..3
// (idx = 3j+d-1). Per-t chain = nonzero base-4 digits: avg 3.75, max 5 (vs binary
// avg 5.9 / max 10 makespan). K1 critical block (j=4,d=3) = 8 squarings + 2 mults
// = 10 all-LDS phases — same length as the old binary block 9.
//
// K1 hmm_powers_b4: 15 blocks; block b=(j,d) computes E^(4^j) by 2j squarings
//   (split-bf16 MFMA, LDS-only), saves F^T planes, applies (d-1) multiplies by F,
//   writes only its final M[b], Mt[b] (single vmcnt drain).
// K2 hmm_fused_b4: 1024 blocks x 128 thr; wave0 p-chain reads ROWS of Mt (float4,
//   16 loads/step), wave1 q-chain reads ROWS of M; no per-step reductions;
//   log-softmax row; broadcast scatter-write 64 KB/block.

#define TT 1024
#define NK 15   // 15 table entries: idx = 3*j + (d-1)
#define PS 72   // bf16 plane stride in ushorts (144 B rows: 16B-aligned, 2-way banks = free)

typedef short  bf16x8 __attribute__((ext_vector_type(8)));
typedef float  f32x4  __attribute__((ext_vector_type(4)));

__device__ __forceinline__ unsigned short f2bf(float x) {
    unsigned u = __float_as_uint(x);
    unsigned r = u + 0x7fffu + ((u >> 16) & 1u);   // RNE; inputs finite
    return (unsigned short)(r >> 16);
}
__device__ __forceinline__ float bf2f(unsigned short h) {
    return __uint_as_float(((unsigned)h) << 16);
}

__global__ __launch_bounds__(256) void hmm_powers_b4(const float* __restrict__ logA,
                                                     float* __restrict__ M,
                                                     float* __restrict__ Mt) {
    __shared__ unsigned short Ah[64 * PS], Al[64 * PS];   // X row-major hi/lo
    __shared__ unsigned short Th[64 * PS], Tl[64 * PS];   // X transposed hi/lo
    __shared__ unsigned short Fh[64 * PS], Fl[64 * PS];   // saved F^T hi/lo (B-operand)
    __shared__ float red4[4];
    const int b    = blockIdx.x;        // 0..14
    const int j    = b / 3;
    const int d    = b % 3 + 1;
    const int tid  = threadIdx.x;
    const int wid  = tid >> 6;
    const int lane = tid & 63;

    // ---- Phase 0 (identical in all blocks): E = exp(logA)/max.
    {
        const int row = tid >> 2;
        const int c0  = (tid & 3) * 16;
        float v[16];
        float lmax = 0.f;
        #pragma unroll
        for (int jj = 0; jj < 4; ++jj) {
            float4 x = ((const float4*)logA)[row * 16 + (tid & 3) * 4 + jj];
            float e0 = __expf(x.x), e1 = __expf(x.y), e2 = __expf(x.z), e3 = __expf(x.w);
            v[4 * jj + 0] = e0; v[4 * jj + 1] = e1; v[4 * jj + 2] = e2; v[4 * jj + 3] = e3;
            lmax = fmaxf(lmax, fmaxf(fmaxf(e0, e1), fmaxf(e2, e3)));
        }
        #pragma unroll
        for (int off = 32; off > 0; off >>= 1)
            lmax = fmaxf(lmax, __shfl_xor(lmax, off, 64));
        if (lane == 0) red4[wid] = lmax;
        __syncthreads();
        const float sc = 1.f / fmaxf(fmaxf(red4[0], red4[1]), fmaxf(red4[2], red4[3]));

        if (b == 0) {                   // j=0,d=1: table[0] = E itself, done.
            #pragma unroll
            for (int jj = 0; jj < 16; ++jj) {
                float val = v[jj] * sc;
                int cc = c0 + jj;
                M [row * 64 + cc] = val;
                Mt[cc * 64 + row] = val;
            }
            return;
        }
        #pragma unroll
        for (int jj = 0; jj < 16; ++jj) {
            float val = v[jj] * sc;
            unsigned short hi = f2bf(val);
            unsigned short lo = f2bf(val - bf2f(hi));
            int cc = c0 + jj;
            Ah[row * PS + cc] = hi;  Al[row * PS + cc] = lo;
            Th[cc * PS + row] = hi;  Tl[cc * PS + row] = lo;
        }
    }
    __syncthreads();                    // planes = E, valid for first op

    const int quad = lane >> 4;
    const int l15  = lane & 15;
    const int nsq  = 2 * j;             // squarings to reach F = E^(4^j)
    const int nops = nsq + (d - 1);     // then (d-1) multiplies by F

    for (int op = 0; op < nops; ++op) {
        // Save F^T planes once X == E^(4^j) (threads are synced, planes valid here).
        if (op == nsq && d >= 2) {
            const unsigned* sh = (const unsigned*)Th;  unsigned* dh = (unsigned*)Fh;
            const unsigned* sl = (const unsigned*)Tl;  unsigned* dl = (unsigned*)Fl;
            #pragma unroll
            for (int i = 0; i < 9; ++i) {              // 64*PS/2 = 2304 = 256*9 uints
                dh[tid + 256 * i] = sh[tid + 256 * i];
                dl[tid + 256 * i] = sl[tid + 256 * i];
            }
            __syncthreads();
        }
        const unsigned short* Bh = (op < nsq) ? Th : Fh;
        const unsigned short* Bl = (op < nsq) ? Tl : Fl;

        f32x4 acc[4];
        #pragma unroll
        for (int c = 0; c < 4; ++c) acc[c] = (f32x4){0.f, 0.f, 0.f, 0.f};
        #pragma unroll
        for (int kk = 0; kk < 2; ++kk) {
            const int ao = (16 * wid + l15) * PS + 32 * kk + quad * 8;
            bf16x8 ah = *(const bf16x8*)&Ah[ao];
            bf16x8 al = *(const bf16x8*)&Al[ao];
            #pragma unroll
            for (int c = 0; c < 4; ++c) {
                const int bo = (16 * c + l15) * PS + 32 * kk + quad * 8;
                bf16x8 bh = *(const bf16x8*)&Bh[bo];
                bf16x8 bl = *(const bf16x8*)&Bl[bo];
                acc[c] = __builtin_amdgcn_mfma_f32_16x16x32_bf16(ah, bh, acc[c], 0, 0, 0);
                acc[c] = __builtin_amdgcn_mfma_f32_16x16x32_bf16(ah, bl, acc[c], 0, 0, 0);
                acc[c] = __builtin_amdgcn_mfma_f32_16x16x32_bf16(al, bh, acc[c], 0, 0, 0);
            }
        }
        float m = 0.f;
        #pragma unroll
        for (int c = 0; c < 4; ++c)
            #pragma unroll
            for (int r = 0; r < 4; ++r) m = fmaxf(m, acc[c][r]);
        #pragma unroll
        for (int off = 32; off > 0; off >>= 1)
            m = fmaxf(m, __shfl_xor(m, off, 64));
        if (lane == 0) red4[wid] = m;
        __syncthreads();                // all plane/F reads this op done; red4 ready
        const float sc = 1.f / fmaxf(fmaxf(red4[0], red4[1]), fmaxf(red4[2], red4[3]));

        if (op < nops - 1) {            // rewrite planes (LDS only — no drain)
            #pragma unroll
            for (int c = 0; c < 4; ++c) {
                #pragma unroll
                for (int r = 0; r < 4; ++r) {
                    float val = acc[c][r] * sc;
                    const int rr = 16 * wid + quad * 4 + r;   // C/D: row = quad*4+reg (m89)
                    const int cc = 16 * c   + l15;            //      col = lane&15
                    unsigned short hi = f2bf(val);
                    unsigned short lo = f2bf(val - bf2f(hi));
                    Ah[rr * PS + cc] = hi;  Al[rr * PS + cc] = lo;
                    Th[cc * PS + rr] = hi;  Tl[cc * PS + rr] = lo;
                }
            }
            __syncthreads();            // plane writes visible for next op
        } else {                        // final: single global write of table entry b
            float* Mk  = M  + (b << 12);
            float* Mtk = Mt + (b << 12);
            #pragma unroll
            for (int c = 0; c < 4; ++c) {
                #pragma unroll
                for (int r = 0; r < 4; ++r) {
                    float val = acc[c][r] * sc;
                    const int rr = 16 * wid + quad * 4 + r;
                    const int cc = 16 * c   + l15;
                    Mk [rr * 64 + cc] = val;
                    Mtk[cc * 64 + rr] = val;
                }
            }
        }
    }
}

// 1024 blocks x 128 threads: wave 0 -> p-chain (rows of Mt = columns of M),
// wave 1 -> q-chain (rows of M). Base-4 digits of t / 1023-t; <=5 steps per chain,
// 16 float4 row loads per step, no per-step reductions. Then log-softmax row and
// broadcast-write 64 KB to all 256 batches.
__global__ __launch_bounds__(128) void hmm_fused_b4(const float* __restrict__ M,
                                                    const float* __restrict__ Mt,
                                                    const float* __restrict__ logInit,
                                                    float* __restrict__ out) {
    const int t = blockIdx.x;
    __shared__ float sp[64];
    __shared__ float sq[64];
    __shared__ float sgr[64];
    const int lane = threadIdx.x & 63;
    const int w    = threadIdx.x >> 6;

    if (w == 0) {
        sp[lane] = __expf(logInit[lane]);
        const int e = t;
        for (int j = 0; j < 5; ++j) {
            const int dj = (e >> (2 * j)) & 3;
            if (dj) {
                const float4* R = ((const float4*)(Mt + ((3 * j + dj - 1) << 12))) + (lane << 4);
                float a0 = 0.f, a1 = 0.f, a2 = 0.f, a3 = 0.f;
                #pragma unroll
                for (int i = 0; i < 4; ++i) {
                    float4 m0 = R[4 * i + 0], m1 = R[4 * i + 1];
                    float4 m2 = R[4 * i + 2], m3 = R[4 * i + 3];
                    float4 v0 = ((const float4*)sp)[4 * i + 0];
                    float4 v1 = ((const float4*)sp)[4 * i + 1];
                    float4 v2 = ((const float4*)sp)[4 * i + 2];
                    float4 v3 = ((const float4*)sp)[4 * i + 3];
                    a0 = fmaf(m0.x, v0.x, a0); a0 = fmaf(m0.y, v0.y, a0);
                    a0 = fmaf(m0.z, v0.z, a0); a0 = fmaf(m0.w, v0.w, a0);
                    a1 = fmaf(m1.x, v1.x, a1); a1 = fmaf(m1.y, v1.y, a1);
                    a1 = fmaf(m1.z, v1.z, a1); a1 = fmaf(m1.w, v1.w, a1);
                    a2 = fmaf(m2.x, v2.x, a2); a2 = fmaf(m2.y, v2.y, a2);
                    a2 = fmaf(m2.z, v2.z, a2); a2 = fmaf(m2.w, v2.w, a2);
                    a3 = fmaf(m3.x, v3.x, a3); a3 = fmaf(m3.y, v3.y, a3);
                    a3 = fmaf(m3.z, v3.z, a3); a3 = fmaf(m3.w, v3.w, a3);
                }
                sp[lane] = (a0 + a1) + (a2 + a3);   // no rescale: scale cancels in softmax
            }
        }
    } else {
        sq[lane] = 1.f;
        const int e = (TT - 1) - t;
        for (int j = 0; j < 5; ++j) {
            const int dj = (e >> (2 * j)) & 3;
            if (dj) {
                const float4* R = ((const float4*)(M + ((3 * j + dj - 1) << 12))) + (lane << 4);
                float a0 = 0.f, a1 = 0.f, a2 = 0.f, a3 = 0.f;
                #pragma unroll
                for (int i = 0; i < 4; ++i) {
                    float4 m0 = R[4 * i + 0], m1 = R[4 * i + 1];
                    float4 m2 = R[4 * i + 2], m3 = R[4 * i + 3];
                    float4 v0 = ((const float4*)sq)[4 * i + 0];
                    float4 v1 = ((const float4*)sq)[4 * i + 1];
                    float4 v2 = ((const float4*)sq)[4 * i + 2];
                    float4 v3 = ((const float4*)sq)[4 * i + 3];
                    a0 = fmaf(m0.x, v0.x, a0); a0 = fmaf(m0.y, v0.y, a0);
                    a0 = fmaf(m0.z, v0.z, a0); a0 = fmaf(m0.w, v0.w, a0);
                    a1 = fmaf(m1.x, v1.x, a1); a1 = fmaf(m1.y, v1.y, a1);
                    a1 = fmaf(m1.z, v1.z, a1); a1 = fmaf(m1.w, v1.w, a1);
                    a2 = fmaf(m2.x, v2.x, a2); a2 = fmaf(m2.y, v2.y, a2);
                    a2 = fmaf(m2.z, v2.z, a2); a2 = fmaf(m2.w, v2.w, a2);
                    a3 = fmaf(m3.x, v3.x, a3); a3 = fmaf(m3.y, v3.y, a3);
                    a3 = fmaf(m3.z, v3.z, a3); a3 = fmaf(m3.w, v3.w, a3);
                }
                sq[lane] = (a0 + a1) + (a2 + a3);
            }
        }
    }
    __syncthreads();

    if (w == 0) {
        float gv = __logf(sp[lane]) + __logf(sq[lane]);
        float mx = gv;
        #pragma unroll
        for (int off = 32; off > 0; off >>= 1)
            mx = fmaxf(mx, __shfl_xor(mx, off, 64));
        float ex = __expf(gv - mx);
        float sm = ex;
        #pragma unroll
        for (int off = 32; off > 0; off >>= 1)
            sm += __shfl_xor(sm, off, 64);
        sgr[lane] = gv - mx - __logf(sm);
    }
    __syncthreads();

    // Broadcast row t to all 256 batches: out[b][t][0..63], 256-B chunks, float4.
    const int s4 = threadIdx.x & 15;
    const int b0 = threadIdx.x >> 4;                 // 0..7
    float4 val = ((const float4*)sgr)[s4];
    float4* o4 = (float4*)out;
    const size_t trow = (size_t)t * 16 + s4;
    #pragma unroll
    for (int it = 0; it < 32; ++it) {
        int b = (it << 3) + b0;
        o4[(size_t)b * 16384 + trow] = val;
    }
}

extern "C" void kernel_launch(void* const* d_in, const int* in_sizes, int n_in,
                              void* d_out, int out_size, void* d_ws, size_t ws_size,
                              hipStream_t stream) {
    // inputs: [0] observations (unused), [1] log_transition (64x64 f32),
    //         [2] log_initial (64 f32), [3] log_emission (unused)
    const float* logA    = (const float*)d_in[1];
    const float* logInit = (const float*)d_in[2];
    float* M  = (float*)d_ws;              // 15 * 4096 floats
    float* Mt = M + NK * 4096;             // 15 * 4096 floats (480 KB of ws)
    hmm_powers_b4<<<NK, 256, 0, stream>>>(logA, M, Mt);
    hmm_fused_b4<<<TT, 128, 0, stream>>>(M, Mt, logInit, (float*)d_out);
}

// Round 6
// 105.938 us; speedup vs baseline: 1.0540x; 1.0540x over previous
//
#include <hip/hip_runtime.h>

// HMM posterior: out[b,t,s] = log_softmax_s(alphahat[t]+betahat[t]) — batch-independent
// (per-(b,t) emission scalars cancel in the state-axis softmax; observations unused).
// Linear space: p_t = p0 E^t, q_t = E^(1023-t) 1, E = exp(logA)/max. Global scale of
// p,q cancels in the final log-softmax -> NO per-step rescale in the per-t chains
// (p <= 64^10 * e^4 ~ 2^66, fp32-safe; no underflow for N(0,1) logA).
//
// Round-6 structure (3 kernels — each piece individually proven fast):
// K1 hmm_powers_par (round 4): 10 blocks; block b computes squarings 1..b all-LDS
//    (split-bf16 MFMA), writes only M[2^b], Mt[2^b]. Critical path ~4 us.
// K2 hmm_sg (round-4 chain code, coalesced loads): 1024 blocks x 128 thr; binary
//    decomposition matvecs; writes ONE 256-B sg row per block (no 64-KB scatter).
// K3 hmm_bcast (round 1): 2048 blocks x 256 thr; contiguous 32-KB chunks of out.
//    The fused scatter (256-B rows @ 64-KB stride) cycles only ~8 HBM channels per
//    block -> ~2.3 TB/s; contiguous bcast measured at fill-level BW (~5.8 TB/s).

#define TT 1024
#define NK 10
#define PS 72   // bf16 plane stride in ushorts (144 B rows: 16B-aligned, 2-way banks = free)

typedef short  bf16x8 __attribute__((ext_vector_type(8)));
typedef float  f32x4  __attribute__((ext_vector_type(4)));

__device__ __forceinline__ unsigned short f2bf(float x) {
    unsigned u = __float_as_uint(x);
    unsigned r = u + 0x7fffu + ((u >> 16) & 1u);   // RNE; inputs finite
    return (unsigned short)(r >> 16);
}
__device__ __forceinline__ float bf2f(unsigned short h) {
    return __uint_as_float(((unsigned)h) << 16);
}

__global__ __launch_bounds__(256) void hmm_powers_par(const float* __restrict__ logA,
                                                      float* __restrict__ M,
                                                      float* __restrict__ Mt) {
    __shared__ unsigned short Ah[64 * PS], Al[64 * PS];   // row-major hi/lo planes
    __shared__ unsigned short Th[64 * PS], Tl[64 * PS];   // transposed hi/lo planes
    __shared__ float red4[4];
    const int lvl  = blockIdx.x;        // this block produces M[lvl] = E^(2^lvl)
    const int tid  = threadIdx.x;
    const int wid  = tid >> 6;
    const int lane = tid & 63;

    // ---- Phase 0 (identical in all blocks): E0 = exp(logA)/max -> regs (+ planes).
    const int row = tid >> 2;
    const int c0  = (tid & 3) * 16;
    float v[16];
    {
        float lmax = 0.f;
        #pragma unroll
        for (int jj = 0; jj < 4; ++jj) {
            float4 x = ((const float4*)logA)[row * 16 + (tid & 3) * 4 + jj];
            float e0 = __expf(x.x), e1 = __expf(x.y), e2 = __expf(x.z), e3 = __expf(x.w);
            v[4 * jj + 0] = e0; v[4 * jj + 1] = e1; v[4 * jj + 2] = e2; v[4 * jj + 3] = e3;
            lmax = fmaxf(lmax, fmaxf(fmaxf(e0, e1), fmaxf(e2, e3)));
        }
        #pragma unroll
        for (int off = 32; off > 0; off >>= 1)
            lmax = fmaxf(lmax, __shfl_xor(lmax, off, 64));
        if (lane == 0) red4[wid] = lmax;
        __syncthreads();
        const float sc = 1.f / fmaxf(fmaxf(red4[0], red4[1]), fmaxf(red4[2], red4[3]));

        if (lvl == 0) {                 // block 0: write E directly, done.
            #pragma unroll
            for (int j = 0; j < 16; ++j) {
                float val = v[j] * sc;
                int cc = c0 + j;
                M [row * 64 + cc] = val;
                Mt[cc * 64 + row] = val;
            }
            return;
        }
        #pragma unroll
        for (int j = 0; j < 16; ++j) {
            float val = v[j] * sc;
            unsigned short hi = f2bf(val);
            unsigned short lo = f2bf(val - bf2f(hi));
            int cc = c0 + j;
            Ah[row * PS + cc] = hi;  Al[row * PS + cc] = lo;
            Th[cc * PS + row] = hi;  Tl[cc * PS + row] = lo;
        }
    }

    const int quad = lane >> 4;
    const int l15  = lane & 15;

    // ---- squarings 1..lvl, all-LDS; only the last writes global (single drain).
    for (int k = 1; k <= lvl; ++k) {
        __syncthreads();                       // planes = E^(2^(k-1))
        f32x4 acc[4];
        #pragma unroll
        for (int c = 0; c < 4; ++c) acc[c] = (f32x4){0.f, 0.f, 0.f, 0.f};
        #pragma unroll
        for (int kk = 0; kk < 2; ++kk) {
            const int ao = (16 * wid + l15) * PS + 32 * kk + quad * 8;
            bf16x8 ah = *(const bf16x8*)&Ah[ao];
            bf16x8 al = *(const bf16x8*)&Al[ao];
            #pragma unroll
            for (int c = 0; c < 4; ++c) {
                const int bo = (16 * c + l15) * PS + 32 * kk + quad * 8;
                bf16x8 bh = *(const bf16x8*)&Th[bo];
                bf16x8 bl = *(const bf16x8*)&Tl[bo];
                acc[c] = __builtin_amdgcn_mfma_f32_16x16x32_bf16(ah, bh, acc[c], 0, 0, 0);
                acc[c] = __builtin_amdgcn_mfma_f32_16x16x32_bf16(ah, bl, acc[c], 0, 0, 0);
                acc[c] = __builtin_amdgcn_mfma_f32_16x16x32_bf16(al, bh, acc[c], 0, 0, 0);
            }
        }
        float m = 0.f;
        #pragma unroll
        for (int c = 0; c < 4; ++c)
            #pragma unroll
            for (int r = 0; r < 4; ++r) m = fmaxf(m, acc[c][r]);
        #pragma unroll
        for (int off = 32; off > 0; off >>= 1)
            m = fmaxf(m, __shfl_xor(m, off, 64));
        if (lane == 0) red4[wid] = m;
        __syncthreads();                       // frag reads done by all waves; red4 ready
        const float sc = 1.f / fmaxf(fmaxf(red4[0], red4[1]), fmaxf(red4[2], red4[3]));

        if (k < lvl) {                         // rewrite planes (LDS only — no drain)
            #pragma unroll
            for (int c = 0; c < 4; ++c) {
                #pragma unroll
                for (int r = 0; r < 4; ++r) {
                    float val = acc[c][r] * sc;
                    const int rr = 16 * wid + quad * 4 + r;   // C/D: row = quad*4+reg (m89)
                    const int cc = 16 * c   + l15;            //      col = lane&15
                    unsigned short hi = f2bf(val);
                    unsigned short lo = f2bf(val - bf2f(hi));
                    Ah[rr * PS + cc] = hi;  Al[rr * PS + cc] = lo;
                    Th[cc * PS + rr] = hi;  Tl[cc * PS + rr] = lo;
                }
            }
        } else {                               // final level: single global write
            float* Mk  = M  + (lvl << 12);
            float* Mtk = Mt + (lvl << 12);
            #pragma unroll
            for (int c = 0; c < 4; ++c) {
                #pragma unroll
                for (int r = 0; r < 4; ++r) {
                    float val = acc[c][r] * sc;
                    const int rr = 16 * wid + quad * 4 + r;
                    const int cc = 16 * c   + l15;
                    Mk [rr * 64 + cc] = val;
                    Mtk[cc * 64 + rr] = val;
                }
            }
        }
    }
}

// 1024 blocks x 128 threads: wave 0 -> p-chain, wave 1 -> q-chain (wave-coalesced
// scalar loads, no per-step reductions), log-softmax row, write ONE 256-B sg row.
__global__ __launch_bounds__(128) void hmm_sg(const float* __restrict__ M,
                                              const float* __restrict__ Mt,
                                              const float* __restrict__ logInit,
                                              float* __restrict__ sg_ws) {
    const int t = blockIdx.x;
    __shared__ float sp[64];
    __shared__ float sq[64];
    const int lane = threadIdx.x & 63;
    const int w    = threadIdx.x >> 6;

    if (w == 0) {
        sp[lane] = __expf(logInit[lane]);
        const int e = t;
        for (int k = 0; k < NK; ++k) {
            if ((e >> k) & 1) {
                const float* Mk = M + (k << 12);
                float a0 = 0.f, a1 = 0.f, a2 = 0.f, a3 = 0.f;
                #pragma unroll
                for (int i = 0; i < 16; ++i) {
                    a0 = fmaf(sp[i],      Mk[( i       << 6) + lane], a0);
                    a1 = fmaf(sp[i + 16], Mk[((i + 16) << 6) + lane], a1);
                    a2 = fmaf(sp[i + 32], Mk[((i + 32) << 6) + lane], a2);
                    a3 = fmaf(sp[i + 48], Mk[((i + 48) << 6) + lane], a3);
                }
                sp[lane] = (a0 + a1) + (a2 + a3);   // no rescale: scale cancels in softmax
            }
        }
    } else {
        sq[lane] = 1.f;
        const int e = (TT - 1) - t;
        for (int k = 0; k < NK; ++k) {
            if ((e >> k) & 1) {
                const float* Mk = Mt + (k << 12);
                float a0 = 0.f, a1 = 0.f, a2 = 0.f, a3 = 0.f;
                #pragma unroll
                for (int i = 0; i < 16; ++i) {
                    a0 = fmaf(sq[i],      Mk[( i       << 6) + lane], a0);
                    a1 = fmaf(sq[i + 16], Mk[((i + 16) << 6) + lane], a1);
                    a2 = fmaf(sq[i + 32], Mk[((i + 32) << 6) + lane], a2);
                    a3 = fmaf(sq[i + 48], Mk[((i + 48) << 6) + lane], a3);
                }
                sq[lane] = (a0 + a1) + (a2 + a3);
            }
        }
    }
    __syncthreads();

    if (w == 0) {
        float gv = __logf(sp[lane]) + __logf(sq[lane]);
        float mx = gv;
        #pragma unroll
        for (int off = 32; off > 0; off >>= 1)
            mx = fmaxf(mx, __shfl_xor(mx, off, 64));
        float ex = __expf(gv - mx);
        float sm = ex;
        #pragma unroll
        for (int off = 32; off > 0; off >>= 1)
            sm += __shfl_xor(sm, off, 64);
        sg_ws[(t << 6) + lane] = gv - mx - __logf(sm);
    }
}

// Pure broadcast: out[b][t][s] = sg[t][s]. 2048 blocks x 256 threads;
// block (b = bid>>3, q = bid&7) streams a CONTIGUOUS 32-KB chunk of out[b]
// (reads 32 KB of the L2/L3-resident 256-KB sg table, fully coalesced float4).
__global__ __launch_bounds__(256) void hmm_bcast(const float* __restrict__ sg_ws,
                                                 float* __restrict__ out) {
    const int b = blockIdx.x >> 3;
    const int q = blockIdx.x & 7;
    const float4* s4 = (const float4*)sg_ws;
    float4*       o4 = (float4*)out;
    const int tid  = threadIdx.x;
    const int base = (q << 11) + tid;              // float4 units; 2048 f4 per chunk
    const size_t ob = (size_t)b * 16384;           // out[b] start, float4 units
    #pragma unroll
    for (int it = 0; it < 8; ++it) {
        int idx = base + (it << 8);
        o4[ob + idx] = s4[idx];
    }
}

extern "C" void kernel_launch(void* const* d_in, const int* in_sizes, int n_in,
                              void* d_out, int out_size, void* d_ws, size_t ws_size,
                              hipStream_t stream) {
    // inputs: [0] observations (unused), [1] log_transition (64x64 f32),
    //         [2] log_initial (64 f32), [3] log_emission (unused)
    const float* logA    = (const float*)d_in[1];
    const float* logInit = (const float*)d_in[2];
    float* M  = (float*)d_ws;              // 10 * 4096 floats
    float* Mt = M  + NK * 4096;            // 10 * 4096 floats
    float* sg = Mt + NK * 4096;            // 1024 * 64 floats (256 KB)
    hmm_powers_par<<<NK, 256, 0, stream>>>(logA, M, Mt);
    hmm_sg<<<TT, 128, 0, stream>>>(M, Mt, logInit, sg);
    hmm_bcast<<<2048, 256, 0, stream>>>(sg, (float*)d_out);
}

// Round 7
// 101.225 us; speedup vs baseline: 1.1031x; 1.0466x over previous
//
#include <hip/hip_runtime.h>

// HMM posterior: out[b,t,s] = log_softmax_s(alphahat[t]+betahat[t]) — batch-independent
// (per-(b,t) emission scalars cancel in the state-axis softmax; observations unused).
// Linear space: p_t = p0 E^t, q_t = E^(1023-t) 1, E = exp(logA)/max. Global scale of
// p,q cancels in the final log-softmax -> NO per-step rescale in the per-t chains.
//
// Round-7 = round-4 two-dispatch skeleton (best: 101.2) + base-4 chains with the
// COALESCED column-load matvec (round-5 changed decomposition AND load pattern at
// once; the per-lane float4 row gather was the regression, not base-4).
// 1023 = 33333_4: digits of 1023-t are 3-d_j, so per-block makespan =
// max(nz4(t), nz4(1023-t)) avg 4.4 / max 5 (vs binary avg 6.2 / max 10).
//
// K1 hmm_powers_b4: 15 blocks; block b=(j,d) computes E^(4^j) by 2j all-LDS
//    squarings (split-bf16 MFMA), then (d-1) multiplies by saved F^T planes;
//    single global write of M[b], Mt[b] (one vmcnt drain). Critical path = block
//    (j=4,d=3): 10 phases, same as the old binary block 9 (~4 us).
// K2 hmm_fused_b4c: 1024 blocks x 128 thr; wave0 p-chain (coalesced M column
//    loads), wave1 q-chain (Mt); <=5 steps each, no per-step reductions;
//    log-softmax row; fused broadcast scatter-write 64 KB/block (proven equal to
//    contiguous in aggregate, and it saves a launch gap).

#define TT 1024
#define NK 15   // table entries: idx = 3*j + (d-1), j=0..4, d=1..3
#define PS 72   // bf16 plane stride in ushorts (144 B rows: 16B-aligned, 2-way banks = free)

typedef short  bf16x8 __attribute__((ext_vector_type(8)));
typedef float  f32x4  __attribute__((ext_vector_type(4)));

__device__ __forceinline__ unsigned short f2bf(float x) {
    unsigned u = __float_as_uint(x);
    unsigned r = u + 0x7fffu + ((u >> 16) & 1u);   // RNE; inputs finite
    return (unsigned short)(r >> 16);
}
__device__ __forceinline__ float bf2f(unsigned short h) {
    return __uint_as_float(((unsigned)h) << 16);
}

__global__ __launch_bounds__(256) void hmm_powers_b4(const float* __restrict__ logA,
                                                     float* __restrict__ M,
                                                     float* __restrict__ Mt) {
    __shared__ unsigned short Ah[64 * PS], Al[64 * PS];   // X row-major hi/lo
    __shared__ unsigned short Th[64 * PS], Tl[64 * PS];   // X transposed hi/lo
    __shared__ unsigned short Fh[64 * PS], Fl[64 * PS];   // saved F^T hi/lo (B-operand)
    __shared__ float red4[4];
    const int b    = blockIdx.x;        // 0..14
    const int j    = b / 3;
    const int d    = b % 3 + 1;
    const int tid  = threadIdx.x;
    const int wid  = tid >> 6;
    const int lane = tid & 63;

    // ---- Phase 0 (identical in all blocks): E = exp(logA)/max.
    {
        const int row = tid >> 2;
        const int c0  = (tid & 3) * 16;
        float v[16];
        float lmax = 0.f;
        #pragma unroll
        for (int jj = 0; jj < 4; ++jj) {
            float4 x = ((const float4*)logA)[row * 16 + (tid & 3) * 4 + jj];
            float e0 = __expf(x.x), e1 = __expf(x.y), e2 = __expf(x.z), e3 = __expf(x.w);
            v[4 * jj + 0] = e0; v[4 * jj + 1] = e1; v[4 * jj + 2] = e2; v[4 * jj + 3] = e3;
            lmax = fmaxf(lmax, fmaxf(fmaxf(e0, e1), fmaxf(e2, e3)));
        }
        #pragma unroll
        for (int off = 32; off > 0; off >>= 1)
            lmax = fmaxf(lmax, __shfl_xor(lmax, off, 64));
        if (lane == 0) red4[wid] = lmax;
        __syncthreads();
        const float sc = 1.f / fmaxf(fmaxf(red4[0], red4[1]), fmaxf(red4[2], red4[3]));

        if (b == 0) {                   // j=0,d=1: table[0] = E itself, done.
            #pragma unroll
            for (int jj = 0; jj < 16; ++jj) {
                float val = v[jj] * sc;
                int cc = c0 + jj;
                M [row * 64 + cc] = val;
                Mt[cc * 64 + row] = val;
            }
            return;
        }
        #pragma unroll
        for (int jj = 0; jj < 16; ++jj) {
            float val = v[jj] * sc;
            unsigned short hi = f2bf(val);
            unsigned short lo = f2bf(val - bf2f(hi));
            int cc = c0 + jj;
            Ah[row * PS + cc] = hi;  Al[row * PS + cc] = lo;
            Th[cc * PS + row] = hi;  Tl[cc * PS + row] = lo;
        }
    }
    __syncthreads();                    // planes = E, valid for first op

    const int quad = lane >> 4;
    const int l15  = lane & 15;
    const int nsq  = 2 * j;             // squarings to reach F = E^(4^j)
    const int nops = nsq + (d - 1);     // then (d-1) multiplies by F

    for (int op = 0; op < nops; ++op) {
        // Save F^T planes once X == E^(4^j) (threads are synced, planes valid here).
        if (op == nsq && d >= 2) {
            const unsigned* sh = (const unsigned*)Th;  unsigned* dh = (unsigned*)Fh;
            const unsigned* sl = (const unsigned*)Tl;  unsigned* dl = (unsigned*)Fl;
            #pragma unroll
            for (int i = 0; i < 9; ++i) {              // 64*PS/2 = 2304 = 256*9 uints
                dh[tid + 256 * i] = sh[tid + 256 * i];
                dl[tid + 256 * i] = sl[tid + 256 * i];
            }
            __syncthreads();
        }
        const unsigned short* Bh = (op < nsq) ? Th : Fh;
        const unsigned short* Bl = (op < nsq) ? Tl : Fl;

        f32x4 acc[4];
        #pragma unroll
        for (int c = 0; c < 4; ++c) acc[c] = (f32x4){0.f, 0.f, 0.f, 0.f};
        #pragma unroll
        for (int kk = 0; kk < 2; ++kk) {
            const int ao = (16 * wid + l15) * PS + 32 * kk + quad * 8;
            bf16x8 ah = *(const bf16x8*)&Ah[ao];
            bf16x8 al = *(const bf16x8*)&Al[ao];
            #pragma unroll
            for (int c = 0; c < 4; ++c) {
                const int bo = (16 * c + l15) * PS + 32 * kk + quad * 8;
                bf16x8 bh = *(const bf16x8*)&Bh[bo];
                bf16x8 bl = *(const bf16x8*)&Bl[bo];
                acc[c] = __builtin_amdgcn_mfma_f32_16x16x32_bf16(ah, bh, acc[c], 0, 0, 0);
                acc[c] = __builtin_amdgcn_mfma_f32_16x16x32_bf16(ah, bl, acc[c], 0, 0, 0);
                acc[c] = __builtin_amdgcn_mfma_f32_16x16x32_bf16(al, bh, acc[c], 0, 0, 0);
            }
        }
        float m = 0.f;
        #pragma unroll
        for (int c = 0; c < 4; ++c)
            #pragma unroll
            for (int r = 0; r < 4; ++r) m = fmaxf(m, acc[c][r]);
        #pragma unroll
        for (int off = 32; off > 0; off >>= 1)
            m = fmaxf(m, __shfl_xor(m, off, 64));
        if (lane == 0) red4[wid] = m;
        __syncthreads();                // all plane/F reads this op done; red4 ready
        const float sc = 1.f / fmaxf(fmaxf(red4[0], red4[1]), fmaxf(red4[2], red4[3]));

        if (op < nops - 1) {            // rewrite planes (LDS only — no drain)
            #pragma unroll
            for (int c = 0; c < 4; ++c) {
                #pragma unroll
                for (int r = 0; r < 4; ++r) {
                    float val = acc[c][r] * sc;
                    const int rr = 16 * wid + quad * 4 + r;   // C/D: row = quad*4+reg (m89)
                    const int cc = 16 * c   + l15;            //      col = lane&15
                    unsigned short hi = f2bf(val);
                    unsigned short lo = f2bf(val - bf2f(hi));
                    Ah[rr * PS + cc] = hi;  Al[rr * PS + cc] = lo;
                    Th[cc * PS + rr] = hi;  Tl[cc * PS + rr] = lo;
                }
            }
            __syncthreads();            // plane writes visible for next op
        } else {                        // final: single global write of table entry b
            float* Mk  = M  + (b << 12);
            float* Mtk = Mt + (b << 12);
            #pragma unroll
            for (int c = 0; c < 4; ++c) {
                #pragma unroll
                for (int r = 0; r < 4; ++r) {
                    float val = acc[c][r] * sc;
                    const int rr = 16 * wid + quad * 4 + r;
                    const int cc = 16 * c   + l15;
                    Mk [rr * 64 + cc] = val;
                    Mtk[cc * 64 + rr] = val;
                }
            }
        }
    }
}

// 1024 blocks x 128 threads: wave 0 -> p-chain, wave 1 -> q-chain. Base-4 digits
// (<=5 steps/chain), wave-coalesced scalar column loads (256 B/instr), no per-step
// reductions. Then log-softmax row + fused broadcast scatter-write 64 KB/block.
__global__ __launch_bounds__(128) void hmm_fused_b4c(const float* __restrict__ M,
                                                     const float* __restrict__ Mt,
                                                     const float* __restrict__ logInit,
                                                     float* __restrict__ out) {
    const int t = blockIdx.x;
    __shared__ float sp[64];
    __shared__ float sq[64];
    __shared__ float sgr[64];
    const int lane = threadIdx.x & 63;
    const int w    = threadIdx.x >> 6;

    if (w == 0) {
        sp[lane] = __expf(logInit[lane]);
        const int e = t;
        #pragma unroll
        for (int j = 0; j < 5; ++j) {
            const int dj = (e >> (2 * j)) & 3;
            if (dj) {
                const float* Mk = M + ((3 * j + dj - 1) << 12);
                float a0 = 0.f, a1 = 0.f, a2 = 0.f, a3 = 0.f;
                #pragma unroll
                for (int i = 0; i < 16; ++i) {
                    a0 = fmaf(sp[i],      Mk[( i       << 6) + lane], a0);
                    a1 = fmaf(sp[i + 16], Mk[((i + 16) << 6) + lane], a1);
                    a2 = fmaf(sp[i + 32], Mk[((i + 32) << 6) + lane], a2);
                    a3 = fmaf(sp[i + 48], Mk[((i + 48) << 6) + lane], a3);
                }
                sp[lane] = (a0 + a1) + (a2 + a3);   // no rescale: scale cancels in softmax
            }
        }
    } else {
        sq[lane] = 1.f;
        const int e = (TT - 1) - t;
        #pragma unroll
        for (int j = 0; j < 5; ++j) {
            const int dj = (e >> (2 * j)) & 3;
            if (dj) {
                const float* Mk = Mt + ((3 * j + dj - 1) << 12);
                float a0 = 0.f, a1 = 0.f, a2 = 0.f, a3 = 0.f;
                #pragma unroll
                for (int i = 0; i < 16; ++i) {
                    a0 = fmaf(sq[i],      Mk[( i       << 6) + lane], a0);
                    a1 = fmaf(sq[i + 16], Mk[((i + 16) << 6) + lane], a1);
                    a2 = fmaf(sq[i + 32], Mk[((i + 32) << 6) + lane], a2);
                    a3 = fmaf(sq[i + 48], Mk[((i + 48) << 6) + lane], a3);
                }
                sq[lane] = (a0 + a1) + (a2 + a3);
            }
        }
    }
    __syncthreads();

    if (w == 0) {
        float gv = __logf(sp[lane]) + __logf(sq[lane]);
        float mx = gv;
        #pragma unroll
        for (int off = 32; off > 0; off >>= 1)
            mx = fmaxf(mx, __shfl_xor(mx, off, 64));
        float ex = __expf(gv - mx);
        float sm = ex;
        #pragma unroll
        for (int off = 32; off > 0; off >>= 1)
            sm += __shfl_xor(sm, off, 64);
        sgr[lane] = gv - mx - __logf(sm);
    }
    __syncthreads();

    // Broadcast row t to all 256 batches: out[b][t][0..63], 256-B chunks, float4.
    const int s4 = threadIdx.x & 15;
    const int b0 = threadIdx.x >> 4;                 // 0..7
    float4 val = ((const float4*)sgr)[s4];
    float4* o4 = (float4*)out;
    const size_t trow = (size_t)t * 16 + s4;
    #pragma unroll
    for (int it = 0; it < 32; ++it) {
        int b = (it << 3) + b0;
        o4[(size_t)b * 16384 + trow] = val;
    }
}

extern "C" void kernel_launch(void* const* d_in, const int* in_sizes, int n_in,
                              void* d_out, int out_size, void* d_ws, size_t ws_size,
                              hipStream_t stream) {
    // inputs: [0] observations (unused), [1] log_transition (64x64 f32),
    //         [2] log_initial (64 f32), [3] log_emission (unused)
    const float* logA    = (const float*)d_in[1];
    const float* logInit = (const float*)d_in[2];
    float* M  = (float*)d_ws;              // 15 * 4096 floats
    float* Mt = M + NK * 4096;             // 15 * 4096 floats (480 KB of ws)
    hmm_powers_b4<<<NK, 256, 0, stream>>>(logA, M, Mt);
    hmm_fused_b4c<<<TT, 128, 0, stream>>>(M, Mt, logInit, (float*)d_out);
}